// Round 3
// baseline (516.786 us; speedup 1.0000x reference)
//
#include <hip/hip_runtime.h>
#include <math.h>

// predictions, ground_truths: [BS=16, SEQ=4096, SRC=4, DIM=257] float32
// out = sum over (b,src) of sqrt( sum over (seq,dim) diff^2 )
//
// Flat-stream formulation: within batch-slice b, element index
// e = ((s*SRC)+src)*DIM + d  →  (e / 257) & 3 == src.
// So read the slice as dense float4s (16B-aligned, zero predication) and
// classify each element by cheap integer math into 4 accumulators.
#define BS   16
#define SEQ  4096
#define SRC  4
#define DIM  257
#define NBUCKET (BS * SRC)
#define F4_PER_SLICE (SEQ * SRC * DIM / 4)   // 1,052,672
#define U 8                                   // float4s per thread per chunk
#define CHUNK_F4 (256 * U)                    // 2048 float4s per block-chunk
#define NCHUNK (F4_PER_SLICE / CHUNK_F4)      // 514 (exact)
#define BLOCKS_PER_SLICE 257                  // each block: exactly 2 chunks

__global__ __launch_bounds__(256) void sq_sums(
    const float* __restrict__ pred,
    const float* __restrict__ gt,
    float* __restrict__ partial)              // [NBUCKET][BLOCKS_PER_SLICE]
{
    const int b   = blockIdx.y;               // batch slice, block-uniform
    const int blk = blockIdx.x;               // 0..256
    const int t   = threadIdx.x;

    const float4* __restrict__ p4 = (const float4*)pred;
    const float4* __restrict__ g4 = (const float4*)gt;
    const long long sliceBase = (long long)b * F4_PER_SLICE;

    float a0 = 0.f, a1 = 0.f, a2 = 0.f, a3 = 0.f;

    for (int c = blk; c < NCHUNK; c += BLOCKS_PER_SLICE) {
        const int f4InSlice = c * CHUNK_F4 + t;           // < 2^21
        const long long base = sliceBase + f4InSlice;

        // Batch all 16 loads (64 payload VGPRs) before any consumption → MLP.
        float4 P[U], G[U];
        #pragma unroll
        for (int u = 0; u < U; ++u) P[u] = p4[base + u * 256];
        #pragma unroll
        for (int u = 0; u < U; ++u) G[u] = g4[base + u * 256];

        #pragma unroll
        for (int u = 0; u < U; ++u) {
            const unsigned e0 = (unsigned)(f4InSlice + u * 256) * 4u; // elem idx in slice
            const float d0 = P[u].x - G[u].x;
            const float d1 = P[u].y - G[u].y;
            const float d2 = P[u].z - G[u].z;
            const float d3 = P[u].w - G[u].w;
            const float dd[4] = { d0*d0, d1*d1, d2*d2, d3*d3 };
            #pragma unroll
            for (int k = 0; k < 4; ++k) {
                const unsigned s = ((e0 + k) / 257u) & 3u;  // src class
                a0 += (s == 0) ? dd[k] : 0.f;
                a1 += (s == 1) ? dd[k] : 0.f;
                a2 += (s == 2) ? dd[k] : 0.f;
                a3 += (s == 3) ? dd[k] : 0.f;
            }
        }
    }

    // Block reduction: 4 classes × wave shuffle, then LDS across 4 waves.
    const int wave = t >> 6, lane = t & 63;
    #pragma unroll
    for (int o = 32; o > 0; o >>= 1) {
        a0 += __shfl_down(a0, o, 64);
        a1 += __shfl_down(a1, o, 64);
        a2 += __shfl_down(a2, o, 64);
        a3 += __shfl_down(a3, o, 64);
    }
    __shared__ float s4[4][4];                // [wave][class]
    if (lane == 0) { s4[wave][0]=a0; s4[wave][1]=a1; s4[wave][2]=a2; s4[wave][3]=a3; }
    __syncthreads();
    if (t < 4) {
        const float v = s4[0][t] + s4[1][t] + s4[2][t] + s4[3][t];
        partial[(b * 4 + t) * BLOCKS_PER_SLICE + blk] = v;
    }
}

// 256 threads: 4 consecutive threads share one bucket (257 partials each),
// sum → sqrt → wave/LDS reduce → scalar out.
__global__ __launch_bounds__(256) void finalize_kernel(
    const float* __restrict__ partial,
    float* __restrict__ out)
{
    const int t = threadIdx.x;
    const int bucket = t >> 2;
    const int part   = t & 3;
    const int start  = part * 64;
    const int cnt    = (part == 3) ? 65 : 64;   // 64+64+64+65 = 257

    float s = 0.f;
    for (int i = 0; i < cnt; ++i)
        s += partial[bucket * BLOCKS_PER_SLICE + start + i];

    // sum the 4-lane group into lane ≡ 0 (mod 4)
    s += __shfl_down(s, 2, 64);
    s += __shfl_down(s, 1, 64);

    float v = ((t & 3) == 0) ? sqrtf(s) : 0.f;
    #pragma unroll
    for (int o = 32; o > 0; o >>= 1) v += __shfl_down(v, o, 64);

    __shared__ float w4[4];
    const int wave = t >> 6, lane = t & 63;
    if (lane == 0) w4[wave] = v;
    __syncthreads();
    if (t == 0) out[0] = w4[0] + w4[1] + w4[2] + w4[3];
}

extern "C" void kernel_launch(void* const* d_in, const int* in_sizes, int n_in,
                              void* d_out, int out_size, void* d_ws, size_t ws_size,
                              hipStream_t stream)
{
    const float* pred = (const float*)d_in[0];
    const float* gt   = (const float*)d_in[1];
    float* partial = (float*)d_ws;   // 64*257 floats = 65.8 KB, fully overwritten
    float* out     = (float*)d_out;

    sq_sums<<<dim3(BLOCKS_PER_SLICE, BS), 256, 0, stream>>>(pred, gt, partial);
    finalize_kernel<<<1, 256, 0, stream>>>(partial, out);
}